// Round 8
// baseline (41214.786 us; speedup 1.0000x reference)
//
#include <hip/hip_runtime.h>
#include <hip/hip_bf16.h>

#define F_IN  256
#define UNITS 512
#define T_SEQ 1024
#define B_SZ  32
#define NCLS  50
#define NG    16
#define SCOPE __HIP_MEMORY_SCOPE_AGENT

typedef short s16x8 __attribute__((ext_vector_type(8)));
typedef short s16x4 __attribute__((ext_vector_type(4)));
typedef float f32x4v __attribute__((ext_vector_type(4)));
typedef float f32x16 __attribute__((ext_vector_type(16)));

__device__ __forceinline__ ushort f2bf(float f) {
  union { float f; unsigned u; } v; v.f = f;
  unsigned r = v.u + 0x7fffu + ((v.u >> 16) & 1u);   // RNE
  return (ushort)(r >> 16);
}
__device__ __forceinline__ float bf2f(ushort u) {
  union { unsigned i; float f; } v; v.i = ((unsigned)u) << 16; return v.f;
}

union UQ { unsigned long long q; s16x4 v; };

// ==================== shared prep ====================
// WdT [64][1024] bf16 (rows 50..63 zero) from Wd [1024][50]
__global__ void prep_WdT(const float* __restrict__ Wd, ushort* __restrict__ WdT) {
  int idx = blockIdx.x * 256 + threadIdx.x;      // 65536
  int n = idx >> 10, k = idx & 1023;
  float v = (n < NCLS) ? Wd[(size_t)k * NCLS + n] : 0.f;
  WdT[idx] = f2bf(v);
}

// UT[d][n][k<512] = U_d[k][n] ; WT[d][n][k<256] = W_d[k][n]   (bf16)
__global__ void prep_w(const float* __restrict__ Uf, const float* __restrict__ Wf,
                       const float* __restrict__ Ub, const float* __restrict__ Wb,
                       ushort* __restrict__ UT, ushort* __restrict__ WT) {
  int idx = blockIdx.x * 256 + threadIdx.x;      // [2][1536][768]
  int d = idx / (1536 * 768);
  int r = idx % (1536 * 768);
  int n = r / 768, k = r % 768;
  if (k < 512) {
    const float* U = d ? Ub : Uf;
    UT[((size_t)d * 1536 + n) * 512 + k] = f2bf(U[(size_t)k * 1536 + n]);
  } else {
    const float* W = d ? Wb : Wf;
    WT[((size_t)d * 1536 + n) * 256 + (k - 512)] = f2bf(W[(size_t)(k - 512) * 1536 + n]);
  }
}

// ==================== fused producer/consumer kernel ====================
// grid = 132 x 1024 threads.
//   blocks 0..3   : recurrence consumers, dh = blockIdx (d = dh>>1, hb = dh&1).
//                   16 waves, one CU, zero per-step cross-WG sync. h in
//                   double-buffered XOR-swizzled LDS; U B-frags in registers
//                   (96 x s16x8 = 384 VGPR); gates fully in-register.
//   blocks 4..131 : producers, p = blockIdx-4 -> dh = p&3, chunk c = p>>2.
//                   Each computes xg (x-projection + folded bias) for its
//                   32-step chunk into ring slot c&1, then sets ready[dh][c].
//                   Waits (s_sleep poll) for prog[dh] >= c-1 before writing
//                   (ring WAR). All stores agent-scope; ready set after
//                   __syncthreads (drains vmcnt in every wave).
// Consumers poll ready once per 32 steps (amortized); read xg with 8B
// agent-scope atomic loads (ring slots are rewritten -> cached loads unsafe).
// Deadlock-free: prog >= c-1 is published before the consumer requests
// chunk c; 132 WGs all co-resident (<= 2 per CU by threads/LDS).
__global__ __launch_bounds__(1024, 1) void gru_fused(
    const float* __restrict__ x,        // [32][1024][256] f32
    const ushort* __restrict__ UT,      // [2][1536][512] bf16
    const ushort* __restrict__ WT,      // [2][1536][256] bf16
    const float* __restrict__ bias_f,   // [2][1536] f32
    const float* __restrict__ bias_b,
    ushort* __restrict__ xg_ring,       // [2 slot][4 dh][32 sc][96 tile][64 lane][4]
    ushort* __restrict__ h_out,         // [2][1024][32][512] bf16
    unsigned* __restrict__ ready,       // [4 dh][32 c]
    unsigned* __restrict__ prog)        // [4 dh]
{
  const int tid  = threadIdx.x;
  const int wv   = tid >> 6;
  const int lane = tid & 63;
  const int cl   = lane & 15;
  const int khi  = (lane >> 4) << 3;

  __shared__ ushort hl[2][8192];

  if (blockIdx.x >= 4) {
    // ---------------- producer ----------------
    const int p  = blockIdx.x - 4;
    const int dh = p & 3;
    const int c  = p >> 2;
    const int d  = dh >> 1, hb = dh & 1;

    if (c >= 2) {
      if (tid == 0)
        while ((int)__hip_atomic_load(prog + dh, __ATOMIC_RELAXED, SCOPE) < c - 1)
          __builtin_amdgcn_s_sleep(8);
      __syncthreads();
    }

    const float* bias = d ? bias_b : bias_f;
    s16x8 bfr[6][8];
    float bv[6];
    #pragma unroll
    for (int u = 0; u < 6; ++u) {
      int colg = (wv * 6 + u) * 16 + cl;
      const ushort* wp = WT + ((size_t)d * 1536 + colg) * 256 + khi;
      #pragma unroll
      for (int ks = 0; ks < 8; ++ks) bfr[u][ks] = *(const s16x8*)(wp + ks * 32);
      bv[u] = bias[colg] + (colg < 1024 ? bias[1536 + colg] : 0.f);
    }

    for (int sc = 0; sc < 32; ++sc) {
      const int s = c * 32 + sc;
      const int t = d ? (T_SEQ - 1 - s) : s;
      const float* xp = x + ((size_t)(hb * 16 + cl) * T_SEQ + t) * F_IN + khi;
      s16x8 afr[8];
      #pragma unroll
      for (int ks = 0; ks < 8; ++ks) {
        float4 f0 = *(const float4*)(xp + ks * 32);
        float4 f1 = *(const float4*)(xp + ks * 32 + 4);
        s16x8 a;
        a[0] = (short)f2bf(f0.x); a[1] = (short)f2bf(f0.y);
        a[2] = (short)f2bf(f0.z); a[3] = (short)f2bf(f0.w);
        a[4] = (short)f2bf(f1.x); a[5] = (short)f2bf(f1.y);
        a[6] = (short)f2bf(f1.z); a[7] = (short)f2bf(f1.w);
        afr[ks] = a;
      }
      #pragma unroll
      for (int u = 0; u < 6; ++u) {
        f32x4v acc = {0.f, 0.f, 0.f, 0.f};
        #pragma unroll
        for (int ks = 0; ks < 8; ++ks)
          acc = __builtin_amdgcn_mfma_f32_16x16x32_bf16(afr[ks], bfr[u][ks], acc, 0, 0, 0);
        UQ o;
        #pragma unroll
        for (int i = 0; i < 4; ++i) o.v[i] = (short)f2bf(acc[i] + bv[u]);
        ushort* dst = xg_ring + ((size_t)(((c & 1) * 4 + dh) * 32 + sc) * 96
                                 + (wv * 6 + u)) * 256 + lane * 4;
        __hip_atomic_store((unsigned long long*)dst, o.q, __ATOMIC_RELAXED, SCOPE);
      }
    }
    __syncthreads();   // drains vmcnt in every wave -> chunk fully published
    if (tid == 0)
      __hip_atomic_store(ready + dh * 32 + c, 1u, __ATOMIC_RELAXED, SCOPE);
    return;
  }

  // ---------------- consumer (recurrence) ----------------
  const int dh = blockIdx.x;
  const int d  = dh >> 1, hb = dh & 1;
  const int rowbase = (lane >> 4) << 2;

  {  // zero h buffer 0 (h0 = 0)
    s16x8 z8 = {0, 0, 0, 0, 0, 0, 0, 0};
    *(s16x8*)(&hl[0][tid * 8]) = z8;
  }

  // U^T B-fragments: 96 x s16x8 (384 VGPR), static indexing
  s16x8 bf0[2][16], bf1[2][16], bf2[2][16];
  {
    const ushort* base = UT + ((size_t)d * 1536) * 512;
    #pragma unroll
    for (int u = 0; u < 2; ++u) {
      const ushort* p0 = base + (size_t)(0 * 512 + wv * 32 + u * 16 + cl) * 512 + khi;
      const ushort* p1 = base + (size_t)(1 * 512 + wv * 32 + u * 16 + cl) * 512 + khi;
      const ushort* p2 = base + (size_t)(2 * 512 + wv * 32 + u * 16 + cl) * 512 + khi;
      #pragma unroll
      for (int ks = 0; ks < 16; ++ks) {
        bf0[u][ks] = *(const s16x8*)(p0 + ks * 32);
        bf1[u][ks] = *(const s16x8*)(p1 + ks * 32);
        bf2[u][ks] = *(const s16x8*)(p2 + ks * 32);
      }
    }
  }

  const float* bias = d ? bias_b : bias_f;
  const float brh0 = bias[1536 + 1024 + wv * 32 + cl];
  const float brh1 = bias[1536 + 1024 + wv * 32 + 16 + cl];

  float hp0[4], hp1[4];
  #pragma unroll
  for (int i = 0; i < 4; ++i) { hp0[i] = 0.f; hp1[i] = 0.f; }

  __syncthreads();

  for (int s = 0; s < T_SEQ; ++s) {
    const int t  = d ? (T_SEQ - 1 - s) : s;
    const int pb = s & 1;
    const int cb = pb ^ 1;

    if ((s & 31) == 0) {        // chunk boundary: wait for producer
      if (tid == 0)
        while (__hip_atomic_load(ready + dh * 32 + (s >> 5), __ATOMIC_RELAXED, SCOPE) == 0)
          __builtin_amdgcn_s_sleep(2);
      __syncthreads();
    }

    // xg loads (8B agent atomics, issued early, hidden under MFMAs)
    const size_t ringb = ((size_t)(((s >> 5) & 1) * 4 + dh) * 32 + (s & 31)) * 96;
    UQ xq[6];
    #pragma unroll
    for (int g = 0; g < 3; ++g) {
      #pragma unroll
      for (int u = 0; u < 2; ++u) {
        const ushort* src = xg_ring + (ringb + (size_t)(g * 32 + wv * 2 + u)) * 256 + lane * 4;
        xq[g * 2 + u].q = __hip_atomic_load((const unsigned long long*)src,
                                            __ATOMIC_RELAXED, SCOPE);
      }
    }

    f32x4v az0 = {0.f,0.f,0.f,0.f}, az1 = {0.f,0.f,0.f,0.f};
    f32x4v ar0 = {0.f,0.f,0.f,0.f}, ar1 = {0.f,0.f,0.f,0.f};
    f32x4v ah0 = {0.f,0.f,0.f,0.f}, ah1 = {0.f,0.f,0.f,0.f};

    const ushort* hbase = &hl[pb][cl * 512];
    const int swz = (cl & 7) << 3;
    #pragma unroll
    for (int ks = 0; ks < 16; ++ks) {
      s16x8 a = *(const s16x8*)(hbase + (((ks * 32) + khi) ^ swz));
      az0 = __builtin_amdgcn_mfma_f32_16x16x32_bf16(a, bf0[0][ks], az0, 0, 0, 0);
      az1 = __builtin_amdgcn_mfma_f32_16x16x32_bf16(a, bf0[1][ks], az1, 0, 0, 0);
      ar0 = __builtin_amdgcn_mfma_f32_16x16x32_bf16(a, bf1[0][ks], ar0, 0, 0, 0);
      ar1 = __builtin_amdgcn_mfma_f32_16x16x32_bf16(a, bf1[1][ks], ar1, 0, 0, 0);
      ah0 = __builtin_amdgcn_mfma_f32_16x16x32_bf16(a, bf2[0][ks], ah0, 0, 0, 0);
      ah1 = __builtin_amdgcn_mfma_f32_16x16x32_bf16(a, bf2[1][ks], ah1, 0, 0, 0);
    }

    // gate math in-register; h_new -> swizzled LDS + plain global store
    ushort* hw = &hl[cb][0];
    ushort* ho = h_out + ((size_t)(d * T_SEQ + t) * B_SZ + hb * 16) * UNITS;
    #pragma unroll
    for (int i = 0; i < 4; ++i) {
      const int row  = rowbase + i;
      const int rswz = (row & 7) << 3;
      {
        float z  = __builtin_amdgcn_rcpf(1.f + __expf(-(az0[i] + bf2f((ushort)xq[0].v[i]))));
        float r  = __builtin_amdgcn_rcpf(1.f + __expf(-(ar0[i] + bf2f((ushort)xq[2].v[i]))));
        float th = bf2f((ushort)xq[4].v[i]) + r * (ah0[i] + brh0);
        float hh = 1.f - 2.f * __builtin_amdgcn_rcpf(1.f + __expf(2.f * th));
        float hn = z * hp0[i] + (1.f - z) * hh;
        hp0[i] = hn;
        ushort hv = f2bf(hn);
        int j = wv * 32 + cl;
        hw[row * 512 + (j ^ rswz)] = hv;
        ho[(size_t)row * UNITS + j] = hv;
      }
      {
        float z  = __builtin_amdgcn_rcpf(1.f + __expf(-(az1[i] + bf2f((ushort)xq[1].v[i]))));
        float r  = __builtin_amdgcn_rcpf(1.f + __expf(-(ar1[i] + bf2f((ushort)xq[3].v[i]))));
        float th = bf2f((ushort)xq[5].v[i]) + r * (ah1[i] + brh1);
        float hh = 1.f - 2.f * __builtin_amdgcn_rcpf(1.f + __expf(2.f * th));
        float hn = z * hp1[i] + (1.f - z) * hh;
        hp1[i] = hn;
        ushort hv = f2bf(hn);
        int j = wv * 32 + 16 + cl;
        hw[row * 512 + (j ^ rswz)] = hv;
        ho[(size_t)row * UNITS + j] = hv;
      }
    }
    __syncthreads();   // LDS writes complete before next step reads them

    if ((s & 31) == 31 && tid == 0)
      __hip_atomic_store(prog + dh, (unsigned)((s >> 5) + 1), __ATOMIC_RELAXED, SCOPE);
  }
}

// ==================== FALLBACK (R5, proven) ====================
__global__ void prep_xT(const float* __restrict__ x, ushort* __restrict__ xT) {
  int idx = blockIdx.x * 256 + threadIdx.x;
  int b = idx >> 15; int r = idx & 32767; int t = r >> 5; int c = r & 31;
  const float4* s4 = (const float4*)(x + ((size_t)b * T_SEQ + t) * F_IN + c * 8);
  float4 f0 = s4[0], f1 = s4[1];
  s16x8 o;
  o[0] = (short)f2bf(f0.x); o[1] = (short)f2bf(f0.y);
  o[2] = (short)f2bf(f0.z); o[3] = (short)f2bf(f0.w);
  o[4] = (short)f2bf(f1.x); o[5] = (short)f2bf(f1.y);
  o[6] = (short)f2bf(f1.z); o[7] = (short)f2bf(f1.w);
  *(s16x8*)(xT + ((size_t)t * B_SZ + b) * F_IN + c * 8) = o;
}

__global__ void prep_UWT(const float* __restrict__ Uf, const float* __restrict__ Wf,
                         const float* __restrict__ Ub, const float* __restrict__ Wb,
                         ushort* __restrict__ UWT) {
  int idx = blockIdx.x * 256 + threadIdx.x;
  int d = idx / 147456; int r = idx % 147456; int n = r / 96; int ck = r % 96;
  const float* U = d ? Ub : Uf;
  const float* W = d ? Wb : Wf;
  s16x8 o;
  #pragma unroll
  for (int i = 0; i < 8; ++i) {
    int k = ck * 8 + i;
    float v = (k < UNITS) ? U[(size_t)k * 1536 + n] : W[(size_t)(k - UNITS) * 1536 + n];
    o[i] = (short)f2bf(v);
  }
  *(s16x8*)(UWT + ((size_t)d * 1536 + n) * 768 + ck * 8) = o;
}

__global__ __launch_bounds__(384, 2) void gru_rec_fb(
    const ushort* __restrict__ xT, const ushort* __restrict__ UWT,
    const float* __restrict__ bias_f, const float* __restrict__ bias_b,
    ushort* __restrict__ h_out, unsigned* __restrict__ tags)
{
  const int g  = blockIdx.x;
  const int d  = g >> 4;
  const int gg = g & 15;
  const int tid  = threadIdx.x;
  const int wv   = tid >> 6;
  const int lane = tid & 63;
  const int col  = lane & 31;
  const int half = lane >> 5;
  const int gate = wv >> 1;
  const int kh   = wv & 1;

  __shared__ float slot[2][32][128];

  s16x8 bfrag[24];
  {
    const ushort* bp = UWT + ((size_t)d * 1536 + gate * UNITS + gg * 32 + col) * 768
                       + kh * 384 + half * 8;
    #pragma unroll
    for (int c = 0; c < 24; ++c) bfrag[c] = *(const s16x8*)(bp + c * 16);
  }

  const float* bias = d ? bias_b : bias_f;
  float bz[3], br[3], bih[3], brh[3], hprev[3];
  #pragma unroll
  for (int i = 0; i < 3; ++i) {
    int e = tid + 384 * i;
    int j = gg * 32 + (e & 31);
    bz[i] = br[i] = bih[i] = brh[i] = 0.f;
    hprev[i] = 0.f;
    if (e < 1024) {
      bz[i]  = bias[j]        + bias[1536 + j];
      br[i]  = bias[512 + j]  + bias[1536 + 512 + j];
      bih[i] = bias[1024 + j];
      brh[i] = bias[1536 + 1024 + j];
    }
  }

  for (int s = 0; s < T_SEQ; ++s) {
    const int t_in = d ? (T_SEQ - 1 - s) : s;
    f32x16 acc_a, acc_b;
    #pragma unroll
    for (int i = 0; i < 16; ++i) { acc_a[i] = 0.f; acc_b[i] = 0.f; }

    if (kh) {
      const ushort* xp = xT + ((size_t)t_in * B_SZ + col) * F_IN + half * 8;
      #pragma unroll
      for (int grp = 0; grp < 2; ++grp) {
        s16x8 a[8];
        #pragma unroll
        for (int i = 0; i < 8; ++i) a[i] = *(const s16x8*)(xp + (grp * 8 + i) * 16);
        #pragma unroll
        for (int i = 0; i < 8; ++i)
          acc_b = __builtin_amdgcn_mfma_f32_32x32x16_bf16(a[i], bfrag[8 + grp * 8 + i], acc_b, 0, 0, 0);
      }
    }

    if (s > 0) {
      if (wv == 0) {
        const unsigned expv = (unsigned)s;
        const unsigned* tg = tags + d * NG;
        bool done;
        do {
          unsigned v = (lane < NG)
              ? __hip_atomic_load(tg + lane, __ATOMIC_RELAXED, SCOPE) : expv;
          done = __all(v >= expv);
          if (!done) __builtin_amdgcn_s_sleep(1);
        } while (!done);
      }
      __syncthreads();

      const int t_prev = d ? (T_SEQ - s) : (s - 1);
      const ushort* ap = h_out + ((size_t)(d * T_SEQ + t_prev) * B_SZ + col) * UNITS
                         + kh * 384 + half * 8;
      if (kh) {
        s16x8 a[8];
        #pragma unroll
        for (int i = 0; i < 8; ++i) a[i] = *(const s16x8*)(ap + i * 16);
        #pragma unroll
        for (int i = 0; i < 8; ++i)
          acc_a = __builtin_amdgcn_mfma_f32_32x32x16_bf16(a[i], bfrag[i], acc_a, 0, 0, 0);
      } else {
        #pragma unroll
        for (int grp = 0; grp < 2; ++grp) {
          s16x8 a[12];
          #pragma unroll
          for (int i = 0; i < 12; ++i) a[i] = *(const s16x8*)(ap + (grp * 12 + i) * 16);
          #pragma unroll
          for (int i = 0; i < 12; ++i)
            acc_a = __builtin_amdgcn_mfma_f32_32x32x16_bf16(a[i], bfrag[grp * 12 + i], acc_a, 0, 0, 0);
        }
      }
    }

    #pragma unroll
    for (int i = 0; i < 16; ++i) {
      int brow = (i & 3) + 8 * (i >> 2) + 4 * half;
      if (gate < 2) {
        slot[kh][brow][gate * 32 + col] = acc_a[i] + acc_b[i];
      } else {
        slot[kh][brow][64 + col] = acc_a[i];
        if (kh) slot[1][brow][96 + col] = acc_b[i];
      }
    }
    __syncthreads();

    #pragma unroll
    for (int i = 0; i < 3; ++i) {
      int e = tid + 384 * i;
      if (e < 1024) {
        int b = e >> 5, j = e & 31;
        float rz = slot[0][b][j]      + slot[1][b][j]      + bz[i];
        float rr = slot[0][b][32 + j] + slot[1][b][32 + j] + br[i];
        float rh = slot[0][b][64 + j] + slot[1][b][64 + j] + brh[i];
        float xh = slot[1][b][96 + j] + bih[i];
        rz = fminf(fmaxf(rz, -30.f), 30.f);
        rr = fminf(fmaxf(rr, -30.f), 30.f);
        float z  = 1.f / (1.f + __expf(-rz));
        float rg = 1.f / (1.f + __expf(-rr));
        float ti = xh + rg * rh;
        ti = fminf(fmaxf(ti, -15.f), 15.f);
        float ex = __expf(2.f * ti);
        float hh = (ex - 1.f) / (ex + 1.f);
        float hn = z * hprev[i] + (1.f - z) * hh;
        hprev[i] = hn;
        __hip_atomic_store(
            h_out + ((size_t)(d * T_SEQ + t_in) * B_SZ + b) * UNITS + gg * 32 + j,
            (ushort)f2bf(hn), __ATOMIC_RELAXED, SCOPE);
      }
    }
    __syncthreads();
    if (tid == 0)
      __hip_atomic_store(tags + d * NG + gg, (unsigned)(s + 1),
                         __ATOMIC_RELAXED, SCOPE);
  }
}

// ==================== dense + softmax (proven) ====================
__global__ __launch_bounds__(256) void dense_softmax(
    const ushort* __restrict__ h_out, const ushort* __restrict__ WdT,
    const float* __restrict__ bd, float* __restrict__ out)
{
  const int tid  = threadIdx.x;
  const int w    = tid >> 6, lane = tid & 63;
  const int col  = lane & 31, half = lane >> 5;
  const int t = blockIdx.x * 4 + w;

  __shared__ float lds[4][32][66];

  f32x16 acc0, acc1;
  #pragma unroll
  for (int i = 0; i < 16; ++i) { acc0[i] = 0.f; acc1[i] = 0.f; }

  const ushort* af  = h_out + ((size_t)t * B_SZ + col) * UNITS + half * 8;
  const ushort* ab  = h_out + ((size_t)(T_SEQ + t) * B_SZ + col) * UNITS + half * 8;
  const ushort* bp0 = WdT + (size_t)col * 1024 + half * 8;
  const ushort* bp1 = WdT + (size_t)(col + 32) * 1024 + half * 8;

  #pragma unroll 4
  for (int ks = 0; ks < 64; ++ks) {
    s16x8 a  = (ks < 32) ? *(const s16x8*)(af + ks * 16)
                         : *(const s16x8*)(ab + (ks - 32) * 16);
    s16x8 b0 = *(const s16x8*)(bp0 + ks * 16);
    s16x8 b1 = *(const s16x8*)(bp1 + ks * 16);
    acc0 = __builtin_amdgcn_mfma_f32_32x32x16_bf16(a, b0, acc0, 0, 0, 0);
    acc1 = __builtin_amdgcn_mfma_f32_32x32x16_bf16(a, b1, acc1, 0, 0, 0);
  }

  #pragma unroll
  for (int i = 0; i < 16; ++i) {
    int b = (i & 3) + 8 * (i >> 2) + 4 * half;
    lds[w][b][col]      = acc0[i];
    lds[w][b][32 + col] = acc1[i];
  }
  __syncthreads();

  if (tid < 128) {
    int tl = tid >> 5, b = tid & 31;
    int tt = blockIdx.x * 4 + tl;
    float v[NCLS];
    float m = -1e30f;
    #pragma unroll
    for (int c = 0; c < NCLS; ++c) { v[c] = lds[tl][b][c] + bd[c]; m = fmaxf(m, v[c]); }
    float sum = 0.f;
    #pragma unroll
    for (int c = 0; c < NCLS; ++c) { float e = __expf(v[c] - m); v[c] = e; sum += e; }
    float inv = 1.f / sum;
    float* op = out + ((size_t)b * T_SEQ + tt) * NCLS;
    #pragma unroll
    for (int c = 0; c < NCLS; ++c) op[c] = v[c] * inv;
  }
}

// ==================== launch ====================
extern "C" void kernel_launch(void* const* d_in, const int* in_sizes, int n_in,
                              void* d_out, int out_size, void* d_ws, size_t ws_size,
                              hipStream_t stream) {
  const float* x  = (const float*)d_in[0];
  const float* Wf = (const float*)d_in[1];
  const float* Uf = (const float*)d_in[2];
  const float* bf = (const float*)d_in[3];
  const float* Wb = (const float*)d_in[4];
  const float* Ub = (const float*)d_in[5];
  const float* bb = (const float*)d_in[6];
  const float* Wd = (const float*)d_in[7];
  const float* bd = (const float*)d_in[8];
  float* out = (float*)d_out;
  char* ws = (char*)d_ws;

  if (ws_size >= 84541968ULL) {
    // ---- fast path: 84.5 MB (< proven 89.5 MB available) ----
    ushort*   UT    = (ushort*)  (ws + 0);           //  3,145,728 B
    ushort*   WT    = (ushort*)  (ws + 3145728);     //  1,572,864 B
    ushort*   WdTp  = (ushort*)  (ws + 4718592);     //    131,072 B
    ushort*   h_buf = (ushort*)  (ws + 4849664);     // 67,108,864 B
    ushort*   xgr   = (ushort*)  (ws + 71958528);    // 12,582,912 B
    unsigned* ready = (unsigned*)(ws + 84541440);    //        512 B
    unsigned* prog  = (unsigned*)(ws + 84541952);    //         16 B

    hipMemsetAsync(ready, 0, 512 + 16, stream);
    hipLaunchKernelGGL(prep_w,        dim3(9216), dim3(256),  0, stream, Uf, Wf, Ub, Wb, UT, WT);
    hipLaunchKernelGGL(prep_WdT,      dim3(256),  dim3(256),  0, stream, Wd, WdTp);
    hipLaunchKernelGGL(gru_fused,     dim3(132),  dim3(1024), 0, stream,
                       x, UT, WT, bf, bb, xgr, h_buf, ready, prog);
    hipLaunchKernelGGL(dense_softmax, dim3(256),  dim3(256),  0, stream, h_buf, WdTp, bd, out);
  } else {
    // ---- fallback: proven R5 pipeline ----
    ushort*   xT    = (ushort*)  (ws + 0);
    ushort*   UWT   = (ushort*)  (ws + 16777216);
    ushort*   WdTp  = (ushort*)  (ws + 21495808);
    ushort*   h_buf = (ushort*)  (ws + 21626880);
    unsigned* tags  = (unsigned*)(ws + 88735744);

    hipMemsetAsync(tags, 0, 2 * NG * sizeof(unsigned), stream);
    hipLaunchKernelGGL(prep_xT,       dim3(4096), dim3(256), 0, stream, x, xT);
    hipLaunchKernelGGL(prep_UWT,      dim3(1152), dim3(256), 0, stream, Uf, Wf, Ub, Wb, UWT);
    hipLaunchKernelGGL(prep_WdT,      dim3(256),  dim3(256), 0, stream, Wd, WdTp);
    hipLaunchKernelGGL(gru_rec_fb,    dim3(32),   dim3(384), 0, stream, xT, UWT, bf, bb, h_buf, tags);
    hipLaunchKernelGGL(dense_softmax, dim3(256),  dim3(256), 0, stream, h_buf, WdTp, bd, out);
  }
}

// Round 9
// 18033.002 us; speedup vs baseline: 2.2855x; 2.2855x over previous
//
#include <hip/hip_runtime.h>
#include <hip/hip_bf16.h>

#define F_IN  256
#define UNITS 512
#define T_SEQ 1024
#define B_SZ  32
#define NCLS  50
#define NG    16
#define SCOPE __HIP_MEMORY_SCOPE_AGENT

typedef short s16x8 __attribute__((ext_vector_type(8)));
typedef float f32x16 __attribute__((ext_vector_type(16)));

__device__ __forceinline__ ushort f2bf(float f) {
  union { float f; unsigned u; } v; v.f = f;
  unsigned r = v.u + 0x7fffu + ((v.u >> 16) & 1u);   // RNE
  return (ushort)(r >> 16);
}

// ---------------- prep kernels (proven) ----------------

// x [32][1024][256] f32  ->  xT [1024][32][256] bf16
__global__ void prep_xT(const float* __restrict__ x, ushort* __restrict__ xT) {
  int idx = blockIdx.x * 256 + threadIdx.x;      // chunk of 8 over [32][1024][32]
  int b = idx >> 15;
  int r = idx & 32767;
  int t = r >> 5;
  int c = r & 31;
  const float4* s4 = (const float4*)(x + ((size_t)b * T_SEQ + t) * F_IN + c * 8);
  float4 f0 = s4[0], f1 = s4[1];
  s16x8 o;
  o[0] = (short)f2bf(f0.x); o[1] = (short)f2bf(f0.y);
  o[2] = (short)f2bf(f0.z); o[3] = (short)f2bf(f0.w);
  o[4] = (short)f2bf(f1.x); o[5] = (short)f2bf(f1.y);
  o[6] = (short)f2bf(f1.z); o[7] = (short)f2bf(f1.w);
  *(s16x8*)(xT + ((size_t)t * B_SZ + b) * F_IN + c * 8) = o;
}

// UWT[d][n][k] bf16, k<512 -> U_d[k][n], k>=512 -> W_d[k-512][n]
__global__ void prep_UWT(const float* __restrict__ Uf, const float* __restrict__ Wf,
                         const float* __restrict__ Ub, const float* __restrict__ Wb,
                         ushort* __restrict__ UWT) {
  int idx = blockIdx.x * 256 + threadIdx.x;      // chunk of 8 over [2][1536][96]
  int d = idx / 147456;
  int r = idx % 147456;
  int n = r / 96;
  int ck = r % 96;
  const float* U = d ? Ub : Uf;
  const float* W = d ? Wb : Wf;
  s16x8 o;
  #pragma unroll
  for (int i = 0; i < 8; ++i) {
    int k = ck * 8 + i;
    float v = (k < UNITS) ? U[(size_t)k * 1536 + n] : W[(size_t)(k - UNITS) * 1536 + n];
    o[i] = (short)f2bf(v);
  }
  *(s16x8*)(UWT + ((size_t)d * 1536 + n) * 768 + ck * 8) = o;
}

// WdT [64][1024] bf16 (rows 50..63 zero) from Wd [1024][50]
__global__ void prep_WdT(const float* __restrict__ Wd, ushort* __restrict__ WdT) {
  int idx = blockIdx.x * 256 + threadIdx.x;      // 65536
  int n = idx >> 10, k = idx & 1023;
  float v = (n < NCLS) ? Wd[(size_t)k * NCLS + n] : 0.f;
  WdT[idx] = f2bf(v);
}

// ---------------- persistent bidirectional GRU recurrence ----------------
// 32 WGs (16/dir) x 384 threads (6 waves; wave = gate(z/r/h) x K-half kh).
// SELF-TAGGED RING protocol (1-hop publish):
//   h word = u32 ((bf16 h)<<16 | (s+1)), agent-stored into ring[d][s&1][b][unit]
//   (256 KB total, L3-resident). Consumer at step s polls ITS OWN fragment
//   words (relaxed agent u64 loads) until every 16-bit tag == s, then unpacks
//   hi16 -> MFMA. No producer drain, no separate tag, no post-poll barrier.
// Ring WAR safety (W=2): a WG writes slot s&1 only after its poll observed
//   ALL WGs' step-(s-1) publishes; publishing step s-1 happens-after that
//   WG's reads of step s-2 (same slot) -> max inter-WG skew is 1 step.
// Tag exact-match (==s): within a replay a slot's tag goes ...,s-1,s+1 ->
//   never falsely matches; ring is memset(0) each launch so first-call
//   garbage never matches (exp >= 1).
// LDS slot is double-buffered -> ONE __syncthreads per step (write(s,p) ->
//   BAR(s) -> read(s,p); write(s+2,p) is after BAR(s+1) which collectively
//   follows every wave's read(s,p)).
// h for dense_softmax goes to h_out via PLAIN stores (off critical path;
//   kernel-completion release makes them visible to the next dispatch).
__global__ __launch_bounds__(384, 2) void gru_rec(
    const ushort* __restrict__ xT,      // [1024][32][256] bf16
    const ushort* __restrict__ UWT,     // [2][1536][768] bf16
    const float* __restrict__ bias_f,   // [2][1536] f32
    const float* __restrict__ bias_b,
    ushort* __restrict__ h_out,         // [2][1024][32][512] bf16
    unsigned* __restrict__ ring)        // [2][2][32][512] u32 self-tagged
{
  const int g  = blockIdx.x;
  const int d  = g >> 4;
  const int gg = g & 15;
  const int tid  = threadIdx.x;
  const int wv   = tid >> 6;
  const int lane = tid & 63;
  const int col  = lane & 31;
  const int half = lane >> 5;
  const int gate = wv >> 1;
  const int kh   = wv & 1;

  __shared__ float slot[2][2][32][128];  // [buf][kh][row][z|r|rh|xh]

  // --- B-fragment preload: 24 chunks of K=16 (96 VGPRs) ---
  s16x8 bfrag[24];
  {
    const ushort* bp = UWT + ((size_t)d * 1536 + gate * UNITS + gg * 32 + col) * 768
                       + kh * 384 + half * 8;
    #pragma unroll
    for (int c = 0; c < 24; ++c) bfrag[c] = *(const s16x8*)(bp + c * 16);
  }

  // --- per-thread gate biases and persistent h state (3 elems/thread) ---
  const float* bias = d ? bias_b : bias_f;
  float bz[3], br[3], bih[3], brh[3], hprev[3];
  #pragma unroll
  for (int i = 0; i < 3; ++i) {
    int e = tid + 384 * i;
    int j = gg * 32 + (e & 31);
    bz[i] = br[i] = bih[i] = brh[i] = 0.f;
    hprev[i] = 0.f;
    if (e < 1024) {
      bz[i]  = bias[j]        + bias[1536 + j];
      br[i]  = bias[512 + j]  + bias[1536 + 512 + j];
      bih[i] = bias[1024 + j];
      brh[i] = bias[1536 + 1024 + j];
    }
  }

  for (int s = 0; s < T_SEQ; ++s) {
    const int t_in = d ? (T_SEQ - 1 - s) : s;
    const int sb   = s & 1;
    f32x16 acc_a, acc_a2, acc_b, acc_b2;
    #pragma unroll
    for (int i = 0; i < 16; ++i) { acc_a[i] = 0.f; acc_a2[i] = 0.f; acc_b[i] = 0.f; acc_b2[i] = 0.f; }

    // x-projection (kh==1 waves, chunks 8..23): overlaps other WGs' publish
    if (kh) {
      const ushort* xp = xT + ((size_t)t_in * B_SZ + col) * F_IN + half * 8;
      s16x8 a[16];
      #pragma unroll
      for (int i = 0; i < 16; ++i) a[i] = *(const s16x8*)(xp + i * 16);
      #pragma unroll
      for (int i = 0; i < 8; ++i) {
        acc_b  = __builtin_amdgcn_mfma_f32_32x32x16_bf16(a[2*i],   bfrag[8 + 2*i],   acc_b,  0, 0, 0);
        acc_b2 = __builtin_amdgcn_mfma_f32_32x32x16_bf16(a[2*i+1], bfrag[8 + 2*i+1], acc_b2, 0, 0, 0);
      }
    }

    if (s > 0) {
      const unsigned expv = (unsigned)s;          // tag of step s-1 data
      const int p = (s - 1) & 1;
      // lane's word base: ring[d][p][col][kh*384 + half*8]
      const unsigned* base = ring + (((size_t)(d * 2 + p) * B_SZ + col) * UNITS)
                             + kh * 384 + half * 8;
      const int nb = kh ? 1 : 3;                  // 8-chunk batches
      #pragma unroll
      for (int b8 = 0; b8 < 3; ++b8) {
        if (b8 >= nb) break;
        unsigned long long q[8][4];
        bool ok;
        do {
          #pragma unroll
          for (int c2 = 0; c2 < 8; ++c2) {
            const unsigned long long* qp =
                (const unsigned long long*)(base + (b8 * 8 + c2) * 16);
            #pragma unroll
            for (int k = 0; k < 4; ++k)
              q[c2][k] = __hip_atomic_load(qp + k, __ATOMIC_RELAXED, SCOPE);
          }
          ok = true;
          #pragma unroll
          for (int c2 = 0; c2 < 8; ++c2)
            #pragma unroll
            for (int k = 0; k < 4; ++k)
              ok = ok && (((unsigned)q[c2][k] & 0xffffu) == expv)
                      && (((unsigned)(q[c2][k] >> 32) & 0xffffu) == expv);
        } while (!__all(ok));
        // unpack hi16 pairs -> s16x8, then MFMA (dual accumulators)
        #pragma unroll
        for (int c2 = 0; c2 < 8; ++c2) {
          union { unsigned u[4]; s16x8 v; } A;
          #pragma unroll
          for (int k = 0; k < 4; ++k)
            A.u[k] = (((unsigned)(q[c2][k] >> 16)) & 0xffffu)
                   | ((unsigned)(q[c2][k] >> 48) << 16);
          int c = b8 * 8 + c2;
          if (c2 & 1) acc_a2 = __builtin_amdgcn_mfma_f32_32x32x16_bf16(A.v, bfrag[c], acc_a2, 0, 0, 0);
          else        acc_a  = __builtin_amdgcn_mfma_f32_32x32x16_bf16(A.v, bfrag[c], acc_a,  0, 0, 0);
        }
      }
    }

    // C/D layout: col = lane&31, row = (reg&3) + 8*(reg>>2) + 4*(lane>>5)
    #pragma unroll
    for (int i = 0; i < 16; ++i) {
      int brow = (i & 3) + 8 * (i >> 2) + 4 * half;
      float ra = acc_a[i] + acc_a2[i];
      float rb = acc_b[i] + acc_b2[i];
      if (gate < 2) {
        slot[sb][kh][brow][gate * 32 + col] = ra + rb;
      } else {
        slot[sb][kh][brow][64 + col] = ra;            // recurrent h-gate partial
        if (kh) slot[sb][1][brow][96 + col] = rb;     // input h-gate part
      }
    }
    __syncthreads();   // the ONE barrier per step

    // gate math + publish: self-tagged ring word (agent) + plain h_out store
    #pragma unroll
    for (int i = 0; i < 3; ++i) {
      int e = tid + 384 * i;
      if (e < 1024) {
        int b = e >> 5, j = e & 31;
        float rz = slot[sb][0][b][j]      + slot[sb][1][b][j]      + bz[i];
        float rr = slot[sb][0][b][32 + j] + slot[sb][1][b][32 + j] + br[i];
        float rh = slot[sb][0][b][64 + j] + slot[sb][1][b][64 + j] + brh[i];
        float xh = slot[sb][1][b][96 + j] + bih[i];
        rz = fminf(fmaxf(rz, -30.f), 30.f);
        rr = fminf(fmaxf(rr, -30.f), 30.f);
        float z  = 1.f / (1.f + __expf(-rz));
        float rg = 1.f / (1.f + __expf(-rr));
        float ti = xh + rg * rh;
        ti = fminf(fmaxf(ti, -15.f), 15.f);
        float ex = __expf(2.f * ti);
        float hh = (ex - 1.f) / (ex + 1.f);
        float hn = z * hprev[i] + (1.f - z) * hh;
        hprev[i] = hn;
        ushort hv = f2bf(hn);
        unsigned w = ((unsigned)hv << 16) | (unsigned)(s + 1);
        __hip_atomic_store(
            ring + (((size_t)(d * 2 + sb) * B_SZ + b) * UNITS) + gg * 32 + j,
            w, __ATOMIC_RELAXED, SCOPE);
        h_out[((size_t)(d * T_SEQ + t_in) * B_SZ + b) * UNITS + gg * 32 + j] = hv;
      }
    }
    // no drain, no tag store, no trailing barrier: the ring words ARE the sync
  }
}

// ---------------- dense + softmax (proven) ----------------
__global__ __launch_bounds__(256) void dense_softmax(
    const ushort* __restrict__ h_out, const ushort* __restrict__ WdT,
    const float* __restrict__ bd, float* __restrict__ out)
{
  const int tid  = threadIdx.x;
  const int w    = tid >> 6, lane = tid & 63;
  const int col  = lane & 31, half = lane >> 5;
  const int t = blockIdx.x * 4 + w;

  __shared__ float lds[4][32][66];

  f32x16 acc0, acc1;
  #pragma unroll
  for (int i = 0; i < 16; ++i) { acc0[i] = 0.f; acc1[i] = 0.f; }

  const ushort* af  = h_out + ((size_t)t * B_SZ + col) * UNITS + half * 8;
  const ushort* ab  = h_out + ((size_t)(T_SEQ + t) * B_SZ + col) * UNITS + half * 8;
  const ushort* bp0 = WdT + (size_t)col * 1024 + half * 8;
  const ushort* bp1 = WdT + (size_t)(col + 32) * 1024 + half * 8;

  #pragma unroll 4
  for (int ks = 0; ks < 64; ++ks) {
    s16x8 a  = (ks < 32) ? *(const s16x8*)(af + ks * 16)
                         : *(const s16x8*)(ab + (ks - 32) * 16);
    s16x8 b0 = *(const s16x8*)(bp0 + ks * 16);
    s16x8 b1 = *(const s16x8*)(bp1 + ks * 16);
    acc0 = __builtin_amdgcn_mfma_f32_32x32x16_bf16(a, b0, acc0, 0, 0, 0);
    acc1 = __builtin_amdgcn_mfma_f32_32x32x16_bf16(a, b1, acc1, 0, 0, 0);
  }

  #pragma unroll
  for (int i = 0; i < 16; ++i) {
    int b = (i & 3) + 8 * (i >> 2) + 4 * half;
    lds[w][b][col]      = acc0[i];
    lds[w][b][32 + col] = acc1[i];
  }
  __syncthreads();

  if (tid < 128) {
    int tl = tid >> 5, b = tid & 31;
    int tt = blockIdx.x * 4 + tl;
    float v[NCLS];
    float m = -1e30f;
    #pragma unroll
    for (int c = 0; c < NCLS; ++c) { v[c] = lds[tl][b][c] + bd[c]; m = fmaxf(m, v[c]); }
    float sum = 0.f;
    #pragma unroll
    for (int c = 0; c < NCLS; ++c) { float e = __expf(v[c] - m); v[c] = e; sum += e; }
    float inv = 1.f / sum;
    float* op = out + ((size_t)b * T_SEQ + tt) * NCLS;
    #pragma unroll
    for (int c = 0; c < NCLS; ++c) op[c] = v[c] * inv;
  }
}

// ---------------- launch ----------------
extern "C" void kernel_launch(void* const* d_in, const int* in_sizes, int n_in,
                              void* d_out, int out_size, void* d_ws, size_t ws_size,
                              hipStream_t stream) {
  const float* x  = (const float*)d_in[0];
  const float* Wf = (const float*)d_in[1];
  const float* Uf = (const float*)d_in[2];
  const float* bf = (const float*)d_in[3];
  const float* Wb = (const float*)d_in[4];
  const float* Ub = (const float*)d_in[5];
  const float* bb = (const float*)d_in[6];
  const float* Wd = (const float*)d_in[7];
  const float* bd = (const float*)d_in[8];
  float* out = (float*)d_out;

  char* ws = (char*)d_ws;
  ushort*   xT    = (ushort*)  (ws + 0);          // 16,777,216 B
  ushort*   UWT   = (ushort*)  (ws + 16777216);   //  4,718,592 B
  ushort*   WdTp  = (ushort*)  (ws + 21495808);   //    131,072 B
  ushort*   h_buf = (ushort*)  (ws + 21626880);   // 67,108,864 B
  unsigned* ring  = (unsigned*)(ws + 88735744);   //    262,144 B  (total ~89.0 MB, <= proven 89.5)

  hipMemsetAsync(ring, 0, 2 * 2 * B_SZ * UNITS * sizeof(unsigned), stream);
  hipLaunchKernelGGL(prep_xT,       dim3(4096), dim3(256), 0, stream, x, xT);
  hipLaunchKernelGGL(prep_UWT,      dim3(1152), dim3(256), 0, stream, Uf, Wf, Ub, Wb, UWT);
  hipLaunchKernelGGL(prep_WdT,      dim3(256),  dim3(256), 0, stream, Wd, WdTp);
  hipLaunchKernelGGL(gru_rec,       dim3(32),   dim3(384), 0, stream, xT, UWT, bf, bb, h_buf, ring);
  hipLaunchKernelGGL(dense_softmax, dim3(256),  dim3(256), 0, stream, h_buf, WdTp, bd, out);
}

// Round 10
// 7336.156 us; speedup vs baseline: 5.6180x; 2.4581x over previous
//
#include <hip/hip_runtime.h>
#include <hip/hip_bf16.h>

#define F_IN  256
#define UNITS 512
#define T_SEQ 1024
#define B_SZ  32
#define NCLS  50
#define NG    16
#define SCOPE __HIP_MEMORY_SCOPE_AGENT

typedef short s16x8 __attribute__((ext_vector_type(8)));
typedef float f32x16 __attribute__((ext_vector_type(16)));

__device__ __forceinline__ ushort f2bf(float f) {
  union { float f; unsigned u; } v; v.f = f;
  unsigned r = v.u + 0x7fffu + ((v.u >> 16) & 1u);   // RNE
  return (ushort)(r >> 16);
}

// L2-executed read that can never be served stale from L1: atomic cmpxchg
// with an impossible compare value (tags are <= 1025, never 0xFFFFFFFF).
// Global atomics execute at L2 (L1 has no atomic path); failed CAS writes
// nothing and returns the observed value. Not foldable to a cached load.
__device__ __forceinline__ unsigned l2_read(unsigned* p) {
  unsigned expected = 0xFFFFFFFFu;
  __hip_atomic_compare_exchange_strong(p, &expected, 0xFFFFFFFFu,
      __ATOMIC_RELAXED, __ATOMIC_RELAXED, __HIP_MEMORY_SCOPE_WORKGROUP);
  return expected;
}

// ---------------- prep kernels (proven) ----------------

// x [32][1024][256] f32  ->  xT [1024][32][256] bf16
__global__ void prep_xT(const float* __restrict__ x, ushort* __restrict__ xT) {
  int idx = blockIdx.x * 256 + threadIdx.x;      // chunk of 8 over [32][1024][32]
  int b = idx >> 15;
  int r = idx & 32767;
  int t = r >> 5;
  int c = r & 31;
  const float4* s4 = (const float4*)(x + ((size_t)b * T_SEQ + t) * F_IN + c * 8);
  float4 f0 = s4[0], f1 = s4[1];
  s16x8 o;
  o[0] = (short)f2bf(f0.x); o[1] = (short)f2bf(f0.y);
  o[2] = (short)f2bf(f0.z); o[3] = (short)f2bf(f0.w);
  o[4] = (short)f2bf(f1.x); o[5] = (short)f2bf(f1.y);
  o[6] = (short)f2bf(f1.z); o[7] = (short)f2bf(f1.w);
  *(s16x8*)(xT + ((size_t)t * B_SZ + b) * F_IN + c * 8) = o;
}

// UWT[d][n][k] bf16, k<512 -> U_d[k][n], k>=512 -> W_d[k-512][n]
__global__ void prep_UWT(const float* __restrict__ Uf, const float* __restrict__ Wf,
                         const float* __restrict__ Ub, const float* __restrict__ Wb,
                         ushort* __restrict__ UWT) {
  int idx = blockIdx.x * 256 + threadIdx.x;      // chunk of 8 over [2][1536][96]
  int d = idx / 147456;
  int r = idx % 147456;
  int n = r / 96;
  int ck = r % 96;
  const float* U = d ? Ub : Uf;
  const float* W = d ? Wb : Wf;
  s16x8 o;
  #pragma unroll
  for (int i = 0; i < 8; ++i) {
    int k = ck * 8 + i;
    float v = (k < UNITS) ? U[(size_t)k * 1536 + n] : W[(size_t)(k - UNITS) * 1536 + n];
    o[i] = (short)f2bf(v);
  }
  *(s16x8*)(UWT + ((size_t)d * 1536 + n) * 768 + ck * 8) = o;
}

// WdT [64][1024] bf16 (rows 50..63 zero) from Wd [1024][50]
__global__ void prep_WdT(const float* __restrict__ Wd, ushort* __restrict__ WdT) {
  int idx = blockIdx.x * 256 + threadIdx.x;      // 65536
  int n = idx >> 10, k = idx & 1023;
  float v = (n < NCLS) ? Wd[(size_t)k * NCLS + n] : 0.f;
  WdT[idx] = f2bf(v);
}

// ---------------- persistent bidirectional GRU recurrence ----------------
// R6 structure (XCD-pinned, passing) with the exchange moved INTO the XCD L2:
//   * 512 WGs launched; WGs on XCD0 claim the 16 fwd slots, XCD1 the 16 bwd
//     slots (agent atomic, R6-proven); others exit. All 16 WGs of a direction
//     share one XCD -> its L2 is a valid coherence point for them.
//   * producer: gate math -> PLAIN h stores (write-through L1 -> local L2)
//     -> __syncthreads (vmcnt(0): stores acked by L2) -> PLAIN tag store.
//   * consumer: wave 0 polls the 16 tags via l2_read (CAS at L2 - never
//     L1-stale, never bypasses to L3); __syncthreads; payload via PLAIN
//     cached loads of fresh addresses (L1 miss -> L2 HIT on the dirty line).
// No L3/fabric hop anywhere on the steady-state critical path.
// LDS WAR safety (3 barriers, R5/R6-proven): slot written (B1..B2), read
// (B2..B3); own tag >= s+1 implies own B3(s) passed -> next write safe.
__global__ __launch_bounds__(384, 2) void gru_rec(
    const ushort* __restrict__ xT,      // [1024][32][256] bf16
    const ushort* __restrict__ UWT,     // [2][1536][768] bf16
    const float* __restrict__ bias_f,   // [2][1536] f32
    const float* __restrict__ bias_b,
    ushort* __restrict__ h_out,         // [2][1024][32][512] bf16
    unsigned* __restrict__ tags,        // [2][16] monotone step counters
    unsigned* __restrict__ claim)       // [2] slot claim counters
{
  const int tid  = threadIdx.x;

  unsigned xcc;
  asm volatile("s_getreg_b32 %0, hwreg(HW_REG_XCC_ID)" : "=s"(xcc));

  __shared__ int s_slot;
  if (tid == 0) {
    int sl = -1;
    if (xcc <= 1) {
      unsigned t = __hip_atomic_fetch_add(&claim[xcc], 1u, __ATOMIC_RELAXED, SCOPE);
      if (t < NG) sl = (int)(xcc * NG + t);
    }
    s_slot = sl;
  }
  __syncthreads();
  if (s_slot < 0) return;
  const int d  = s_slot >> 4;    // direction == XCD id
  const int gg = s_slot & 15;

  const int wv   = tid >> 6;
  const int lane = tid & 63;
  const int col  = lane & 31;
  const int half = lane >> 5;
  const int gate = wv >> 1;
  const int kh   = wv & 1;

  __shared__ float slot[2][32][128];  // [kh][row][ z | r | rh | xh ]

  // --- B-fragment preload: 24 chunks of K=16 (96 VGPRs) ---
  s16x8 bfrag[24];
  {
    const ushort* bp = UWT + ((size_t)d * 1536 + gate * UNITS + gg * 32 + col) * 768
                       + kh * 384 + half * 8;
    #pragma unroll
    for (int c = 0; c < 24; ++c) bfrag[c] = *(const s16x8*)(bp + c * 16);
  }

  // --- per-thread gate biases and persistent h state (3 elems/thread) ---
  const float* bias = d ? bias_b : bias_f;
  float bz[3], br[3], bih[3], brh[3], hprev[3];
  #pragma unroll
  for (int i = 0; i < 3; ++i) {
    int e = tid + 384 * i;
    int j = gg * 32 + (e & 31);
    bz[i] = br[i] = bih[i] = brh[i] = 0.f;
    hprev[i] = 0.f;
    if (e < 1024) {
      bz[i]  = bias[j]        + bias[1536 + j];
      br[i]  = bias[512 + j]  + bias[1536 + 512 + j];
      bih[i] = bias[1024 + j];
      brh[i] = bias[1536 + 1024 + j];
    }
  }

  for (int s = 0; s < T_SEQ; ++s) {
    const int t_in = d ? (T_SEQ - 1 - s) : s;
    f32x16 acc_a, acc_a2, acc_b, acc_b2;
    #pragma unroll
    for (int i = 0; i < 16; ++i) { acc_a[i] = 0.f; acc_a2[i] = 0.f; acc_b[i] = 0.f; acc_b2[i] = 0.f; }

    // x-projection (kh==1 waves). Wave 0 (kh=0,z) goes straight to the poll.
    if (kh) {
      const ushort* xp = xT + ((size_t)t_in * B_SZ + col) * F_IN + half * 8;
      s16x8 a[16];
      #pragma unroll
      for (int i = 0; i < 16; ++i) a[i] = *(const s16x8*)(xp + i * 16);
      #pragma unroll
      for (int i = 0; i < 8; ++i) {
        acc_b  = __builtin_amdgcn_mfma_f32_32x32x16_bf16(a[2*i],   bfrag[8 + 2*i],   acc_b,  0, 0, 0);
        acc_b2 = __builtin_amdgcn_mfma_f32_32x32x16_bf16(a[2*i+1], bfrag[8 + 2*i+1], acc_b2, 0, 0, 0);
      }
    }

    if (s > 0) {
      if (wv == 0) {
        const unsigned expv = (unsigned)s;
        unsigned* tg = tags + d * NG;
        bool done;
        do {
          unsigned v = (lane < NG) ? l2_read(tg + lane) : expv;
          done = __all(v >= expv);
          if (!done) __builtin_amdgcn_s_sleep(1);
        } while (!done);
      }
      __syncthreads();   // B1: release all waves

      const int t_prev = d ? (T_SEQ - s) : (s - 1);
      const ushort* ap = h_out + ((size_t)(d * T_SEQ + t_prev) * B_SZ + col) * UNITS
                         + kh * 384 + half * 8;
      if (kh) {               // h[384:512): 8 fragments, 2 accs
        s16x8 a[8];
        #pragma unroll
        for (int i = 0; i < 8; ++i) a[i] = *(const s16x8*)(ap + i * 16);
        #pragma unroll
        for (int i = 0; i < 4; ++i) {
          acc_a  = __builtin_amdgcn_mfma_f32_32x32x16_bf16(a[2*i],   bfrag[2*i],   acc_a,  0, 0, 0);
          acc_a2 = __builtin_amdgcn_mfma_f32_32x32x16_bf16(a[2*i+1], bfrag[2*i+1], acc_a2, 0, 0, 0);
        }
      } else {                // h[0:384): 24 fragments, 2 batches of 12, 2 accs
        #pragma unroll
        for (int grp = 0; grp < 2; ++grp) {
          s16x8 a[12];
          #pragma unroll
          for (int i = 0; i < 12; ++i) a[i] = *(const s16x8*)(ap + (grp * 12 + i) * 16);
          #pragma unroll
          for (int i = 0; i < 6; ++i) {
            acc_a  = __builtin_amdgcn_mfma_f32_32x32x16_bf16(a[2*i],   bfrag[grp*12 + 2*i],   acc_a,  0, 0, 0);
            acc_a2 = __builtin_amdgcn_mfma_f32_32x32x16_bf16(a[2*i+1], bfrag[grp*12 + 2*i+1], acc_a2, 0, 0, 0);
          }
        }
      }
    }

    // C/D layout: col = lane&31, row = (reg&3) + 8*(reg>>2) + 4*(lane>>5)
    #pragma unroll
    for (int i = 0; i < 16; ++i) {
      int brow = (i & 3) + 8 * (i >> 2) + 4 * half;
      float ra = acc_a[i] + acc_a2[i];
      float rb = acc_b[i] + acc_b2[i];
      if (gate < 2) {
        slot[kh][brow][gate * 32 + col] = ra + rb;
      } else {
        slot[kh][brow][64 + col] = ra;               // recurrent h-gate partial
        if (kh) slot[1][brow][96 + col] = rb;        // input h-gate part
      }
    }
    __syncthreads();   // B2: slot complete

    // gate math + publish h_new (PLAIN stores -> write-through into local L2)
    #pragma unroll
    for (int i = 0; i < 3; ++i) {
      int e = tid + 384 * i;
      if (e < 1024) {
        int b = e >> 5, j = e & 31;
        float rz = slot[0][b][j]      + slot[1][b][j]      + bz[i];
        float rr = slot[0][b][32 + j] + slot[1][b][32 + j] + br[i];
        float rh = slot[0][b][64 + j] + slot[1][b][64 + j] + brh[i];
        float xh = slot[1][b][96 + j] + bih[i];
        rz = fminf(fmaxf(rz, -30.f), 30.f);
        rr = fminf(fmaxf(rr, -30.f), 30.f);
        float z  = 1.f / (1.f + __expf(-rz));
        float rg = 1.f / (1.f + __expf(-rr));
        float ti = xh + rg * rh;
        ti = fminf(fmaxf(ti, -15.f), 15.f);
        float ex = __expf(2.f * ti);
        float hh = (ex - 1.f) / (ex + 1.f);
        float hn = z * hprev[i] + (1.f - z) * hh;
        hprev[i] = hn;
        h_out[((size_t)(d * T_SEQ + t_in) * B_SZ + b) * UNITS + gg * 32 + j] = f2bf(hn);
      }
    }
    // B3: __syncthreads drains vmcnt(0) in every wave -> all 6 waves' h
    // stores are acked by the XCD L2; then ONE plain tag store per WG.
    __syncthreads();
    if (tid == 0)
      *(volatile unsigned*)(tags + d * NG + gg) = (unsigned)(s + 1);
  }
}

// ---------------- dense + softmax (proven) ----------------
__global__ __launch_bounds__(256) void dense_softmax(
    const ushort* __restrict__ h_out, const ushort* __restrict__ WdT,
    const float* __restrict__ bd, float* __restrict__ out)
{
  const int tid  = threadIdx.x;
  const int w    = tid >> 6, lane = tid & 63;
  const int col  = lane & 31, half = lane >> 5;
  const int t = blockIdx.x * 4 + w;

  __shared__ float lds[4][32][66];

  f32x16 acc0, acc1;
  #pragma unroll
  for (int i = 0; i < 16; ++i) { acc0[i] = 0.f; acc1[i] = 0.f; }

  const ushort* af  = h_out + ((size_t)t * B_SZ + col) * UNITS + half * 8;
  const ushort* ab  = h_out + ((size_t)(T_SEQ + t) * B_SZ + col) * UNITS + half * 8;
  const ushort* bp0 = WdT + (size_t)col * 1024 + half * 8;
  const ushort* bp1 = WdT + (size_t)(col + 32) * 1024 + half * 8;

  #pragma unroll 4
  for (int ks = 0; ks < 64; ++ks) {
    s16x8 a  = (ks < 32) ? *(const s16x8*)(af + ks * 16)
                         : *(const s16x8*)(ab + (ks - 32) * 16);
    s16x8 b0 = *(const s16x8*)(bp0 + ks * 16);
    s16x8 b1 = *(const s16x8*)(bp1 + ks * 16);
    acc0 = __builtin_amdgcn_mfma_f32_32x32x16_bf16(a, b0, acc0, 0, 0, 0);
    acc1 = __builtin_amdgcn_mfma_f32_32x32x16_bf16(a, b1, acc1, 0, 0, 0);
  }

  #pragma unroll
  for (int i = 0; i < 16; ++i) {
    int b = (i & 3) + 8 * (i >> 2) + 4 * half;
    lds[w][b][col]      = acc0[i];
    lds[w][b][32 + col] = acc1[i];
  }
  __syncthreads();

  if (tid < 128) {
    int tl = tid >> 5, b = tid & 31;
    int tt = blockIdx.x * 4 + tl;
    float v[NCLS];
    float m = -1e30f;
    #pragma unroll
    for (int c = 0; c < NCLS; ++c) { v[c] = lds[tl][b][c] + bd[c]; m = fmaxf(m, v[c]); }
    float sum = 0.f;
    #pragma unroll
    for (int c = 0; c < NCLS; ++c) { float e = __expf(v[c] - m); v[c] = e; sum += e; }
    float inv = 1.f / sum;
    float* op = out + ((size_t)b * T_SEQ + tt) * NCLS;
    #pragma unroll
    for (int c = 0; c < NCLS; ++c) op[c] = v[c] * inv;
  }
}

// ---------------- launch ----------------
extern "C" void kernel_launch(void* const* d_in, const int* in_sizes, int n_in,
                              void* d_out, int out_size, void* d_ws, size_t ws_size,
                              hipStream_t stream) {
  const float* x  = (const float*)d_in[0];
  const float* Wf = (const float*)d_in[1];
  const float* Uf = (const float*)d_in[2];
  const float* bf = (const float*)d_in[3];
  const float* Wb = (const float*)d_in[4];
  const float* Ub = (const float*)d_in[5];
  const float* bb = (const float*)d_in[6];
  const float* Wd = (const float*)d_in[7];
  const float* bd = (const float*)d_in[8];
  float* out = (float*)d_out;

  char* ws = (char*)d_ws;
  ushort*   xT    = (ushort*)  (ws + 0);          // 16,777,216 B
  ushort*   UWT   = (ushort*)  (ws + 16777216);   //  4,718,592 B
  ushort*   WdTp  = (ushort*)  (ws + 21495808);   //    131,072 B
  ushort*   h_buf = (ushort*)  (ws + 21626880);   // 67,108,864 B
  unsigned* tags  = (unsigned*)(ws + 88735744);   //        128 B
  unsigned* claim = (unsigned*)(ws + 88735872);   //          8 B  (total ~88.7 MB)

  hipMemsetAsync(tags, 0, 2 * NG * sizeof(unsigned) + 2 * sizeof(unsigned), stream);
  hipLaunchKernelGGL(prep_xT,       dim3(4096), dim3(256), 0, stream, x, xT);
  hipLaunchKernelGGL(prep_UWT,      dim3(1152), dim3(256), 0, stream, Uf, Wf, Ub, Wb, UWT);
  hipLaunchKernelGGL(prep_WdT,      dim3(256),  dim3(256), 0, stream, Wd, WdTp);
  hipLaunchKernelGGL(gru_rec,       dim3(512),  dim3(384), 0, stream, xT, UWT, bf, bb, h_buf, tags, claim);
  hipLaunchKernelGGL(dense_softmax, dim3(256),  dim3(256), 0, stream, h_buf, WdTp, bd, out);
}